// Round 8
// baseline (480.532 us; speedup 1.0000x reference)
//
#include <hip/hip_runtime.h>
#include <cmath>

#define NTOK 65536
#define DMOD 1024
#define NEXP 64
#define TOPK 8
#define KCH  64                  // k-chunk staged in LDS (h only)
#define NCH  (DMOD / KCH)
#define STR  65                  // odd stride -> conflict-free ds_read_b128

// token_mask may arrive as 1-byte bool or int32; sniff from the first word.
__device__ __forceinline__ bool tok_mask(const void* tm, int t, int mmode) {
    return mmode == 0 ? (((const unsigned char*)tm)[t] != 0)
                      : (((const unsigned int*)tm)[t] != 0u);
}

__global__ __launch_bounds__(512, 8)
void router_v8(const float* __restrict__ h,
               const float* __restrict__ W,
               const void* __restrict__ tmask,
               float* __restrict__ out)
{
    __shared__ float h_s[2][64][STR];         // 33.3 KB, double-buffered h chunk
    __shared__ float sm_m0[64], sm_inv[64];
    __shared__ unsigned long long mb[64];

    const int tid  = threadIdx.x;
    const int lane = tid & 63;                // = token within block
    const int wave = __builtin_amdgcn_readfirstlane(tid >> 6);  // 0..7, uniform
    const int t0   = blockIdx.x * 64;

    const unsigned int mw = *(const unsigned int*)tmask;
    const int mmode = (mw == 0x01010101u) ? 0 : 1;

    // wave-uniform W base: this wave's 8 expert rows (scalar-pipe loads)
    const float* __restrict__ wbase = W + ((size_t)(wave * 8) << 10);

    // 8 accumulators: (token=lane) x experts 8w..8w+7; strict k-ascending fmaf
    float acc[8];
#pragma unroll
    for (int e = 0; e < 8; ++e) acc[e] = 0.f;

    // h staging map: thread -> row tid>>3 (0..63), cols (tid&7)*8 .. +7
    const int srow = tid >> 3;
    const int scol = (tid & 7) * 8;

    // ---- prologue: stage chunk 0 ----
    {
        const float* hp = h + (size_t)(t0 + srow) * DMOD + scol;
        *reinterpret_cast<float4*>(&h_s[0][srow][scol])     = *reinterpret_cast<const float4*>(hp);
        *reinterpret_cast<float4*>(&h_s[0][srow][scol + 4]) = *reinterpret_cast<const float4*>(hp + 4);
    }
    __syncthreads();

    for (int c = 0; c < NCH; ++c) {
        const int kc  = c * KCH;
        const int cur = c & 1;
        const bool more = (c + 1 < NCH);

        // ---- issue next chunk's global h loads NOW; hidden under compute ----
        float4 g0, g1;
        if (more) {
            const float* hp = h + (size_t)(t0 + srow) * DMOD + kc + KCH + scol;
            g0 = *reinterpret_cast<const float4*>(hp);
            g1 = *reinterpret_cast<const float4*>(hp + 4);
        }

        // ---- compute: per 4-k, 1 ds_read_b128 (h) + 8 scalar W float4 + 32 FMA ----
#pragma unroll 4
        for (int k4 = 0; k4 < KCH / 4; ++k4) {
            const float4 hv = *reinterpret_cast<const float4*>(&h_s[cur][lane][k4 * 4]);
#pragma unroll
            for (int e = 0; e < 8; ++e) {
                const float4 wv = *reinterpret_cast<const float4*>(
                    wbase + ((size_t)e << 10) + kc + k4 * 4);   // wave-uniform -> s_load
                float a = acc[e];
                a = fmaf(hv.x, wv.x, a);
                a = fmaf(hv.y, wv.y, a);
                a = fmaf(hv.z, wv.z, a);
                a = fmaf(hv.w, wv.w, a);
                acc[e] = a;
            }
        }

        // ---- write staged next chunk; single barrier per chunk ----
        if (more) {
            *reinterpret_cast<float4*>(&h_s[cur ^ 1][srow][scol])     = g0;
            *reinterpret_cast<float4*>(&h_s[cur ^ 1][srow][scol + 4]) = g1;
        }
        __syncthreads();
    }

    // ---- logits tile: ls aliases h_s[0] (dead after last chunk's barrier) ----
    float (*ls)[STR] = reinterpret_cast<float(*)[STR]>(&h_s[0][0][0]);

#pragma unroll
    for (int e = 0; e < 8; ++e) ls[lane][wave * 8 + e] = acc[e];

    __syncthreads();

    const size_t P = (size_t)NTOK * NEXP;
    float* __restrict__ o_mask = out;
    float* __restrict__ o_prob = out + P;
    float* __restrict__ o_lc   = out + 2 * P;
    float* __restrict__ o_lsl  = out + 3 * P;
    const size_t base = (size_t)t0 * NEXP;

    // ---- coalesced writes of logits_clean / logits_sel (8 elems/thread) ----
#pragma unroll
    for (int i = 0; i < 8; ++i) {
        const int f = i * 512 + tid;
        const int t = f >> 6, e = f & 63;
        const float lv = ls[t][e];
        const bool tmt = tok_mask(tmask, t0 + t, mmode);
        o_lc[base + f]  = lv;
        o_lsl[base + f] = tmt ? lv : -INFINITY;
    }

    // ---- epilogue: wave0, one token per lane; 8-pass selection-sort top-k ----
    if (wave == 0) {
        const int lt = lane;
        const bool tm = tok_mask(tmask, t0 + lt, mmode);

        unsigned long long bits = 0ULL;
        float m0 = -INFINITY;
        for (int r = 0; r < TOPK; ++r) {
            float bv = -INFINITY; int bi = 0;
            for (int e = 0; e < 64; ++e) {
                if ((bits >> e) & 1ULL) continue;
                const float x = ls[lt][e];
                if (x > bv) { bv = x; bi = e; }
            }
            bits |= 1ULL << bi;
            if (r == 0) m0 = bv;
        }

        float ssum = 0.f;
        for (int e = 0; e < 64; ++e)
            if ((bits >> e) & 1ULL) ssum += expf(ls[lt][e] - m0);

        sm_m0[lt]  = m0;
        sm_inv[lt] = 1.0f / ssum;
        mb[lt] = tm ? bits : 0ULL;            // mb==0 encodes masked token
    }

    __syncthreads();

    // ---- coalesced writes of probs / mask (computed on the fly) ----
#pragma unroll
    for (int i = 0; i < 8; ++i) {
        const int f = i * 512 + tid;
        const int t = f >> 6, e = f & 63;
        const unsigned long long bt = mb[t];
        const bool sel = ((bt >> e) & 1ULL) != 0ULL;
        o_prob[base + f] = sel ? expf(ls[t][e] - sm_m0[t]) * sm_inv[t] : 0.f;
        o_mask[base + f] = sel ? 1.0f : 0.0f;
    }
}

extern "C" void kernel_launch(void* const* d_in, const int* in_sizes, int n_in,
                              void* d_out, int out_size, void* d_ws, size_t ws_size,
                              hipStream_t stream)
{
    const float* h = (const float*)d_in[0];
    const float* W = (const float*)d_in[1];
    const void*  tmask = (const void*)d_in[2];
    float* out = (float*)d_out;

    hipLaunchKernelGGL(router_v8, dim3(NTOK / 64), dim3(512), 0, stream,
                       h, W, tmask, out);
}

// Round 9
// 229.725 us; speedup vs baseline: 2.0918x; 2.0918x over previous
//
#include <hip/hip_runtime.h>
#include <cmath>

#define NTOK 65536
#define DMOD 1024
#define NEXP 64
#define TOPK 8
#define BTOK 128                 // tokens per block
#define KCH  64                  // k-chunk staged in LDS
#define NCH  (DMOD / KCH)
#define HSTR 96                  // LDS row stride (mult of 32 -> swizzle controls banks)

// token_mask may arrive as 1-byte bool or int32; sniff from the first word.
__device__ __forceinline__ bool tok_mask(const void* tm, int t, int mmode) {
    return mmode == 0 ? (((const unsigned char*)tm)[t] != 0)
                      : (((const unsigned int*)tm)[t] != 0u);
}

__global__ __launch_bounds__(128, 1)
void router_v9(const float* __restrict__ h,
               const float* __restrict__ W,
               const void* __restrict__ tmask,
               float* __restrict__ out)
{
    __shared__ float smem[BTOK * HSTR + 64 * HSTR];   // h tile + W tile (73.7 KB)
    __shared__ float sm_m0[BTOK], sm_inv[BTOK];
    __shared__ unsigned long long mb[BTOK];

    float* h_s = smem;                   // [128][96], col-swizzled
    float* w_s = smem + BTOK * HSTR;     // [64][96],  col-swizzled
    float (*ls)[65] = reinterpret_cast<float(*)[65]>(smem);   // epilogue alias (33.3 KB)

    const int tid  = threadIdx.x;
    const int lane = tid & 63;
    const int wave = tid >> 6;           // 0..1
    const int tg   = tid & 15;           // token group: rows 8tg..8tg+7
    const int eg   = tid >> 4;           // expert group: rows 8eg..8eg+7
    const int t0   = blockIdx.x * BTOK;

    const unsigned int mw = *(const unsigned int*)tmask;
    const int mmode = (mw == 0x01010101u) ? 0 : 1;

    // strict sequential fp32 FMA per output, k ascending (np-ref-matching order)
    float acc[8][8];
#pragma unroll
    for (int i = 0; i < 8; ++i)
#pragma unroll
        for (int j = 0; j < 8; ++j) acc[i][j] = 0.f;

    // per-thread LDS read bases (row>>3 is constant within a thread's 8 rows)
    const int hb = tg * 8 * HSTR + 4 * (tg & 7);
    const int wb = eg * 8 * HSTR + 4 * (eg & 7);

    for (int c = 0; c < NCH; ++c) {
        const int kc = c * KCH;

        // ---- stage h tile: 128 rows x 64 k = 2048 float4, 16 per thread ----
#pragma unroll
        for (int p = 0; p < 16; ++p) {
            const int g   = p * 128 + tid;
            const int row = g >> 4;               // 0..127
            const int c4  = (g & 15) * 4;         // 0..60
            const float4 v = *reinterpret_cast<const float4*>(
                h + (size_t)(t0 + row) * DMOD + kc + c4);
            *reinterpret_cast<float4*>(&h_s[row * HSTR + 4 * ((row >> 3) & 7) + c4]) = v;
        }
        // ---- stage W tile: 64 rows x 64 k = 1024 float4, 8 per thread ----
#pragma unroll
        for (int p = 0; p < 8; ++p) {
            const int g   = p * 128 + tid;
            const int row = g >> 4;               // 0..63
            const int c4  = (g & 15) * 4;
            const float4 v = *reinterpret_cast<const float4*>(
                W + ((size_t)row << 10) + kc + c4);
            *reinterpret_cast<float4*>(&w_s[row * HSTR + 4 * ((row >> 3) & 7) + c4]) = v;
        }
        __syncthreads();

        // ---- compute: 8 tokens x 8 experts; per 4-k window 16 ds_read + 256 FMA ----
#pragma unroll 4
        for (int k4 = 0; k4 < KCH / 4; ++k4) {
            float4 hv[8], wv[8];
#pragma unroll
            for (int i = 0; i < 8; ++i)
                hv[i] = *reinterpret_cast<const float4*>(&h_s[hb + i * HSTR + k4 * 4]);
#pragma unroll
            for (int j = 0; j < 8; ++j)
                wv[j] = *reinterpret_cast<const float4*>(&w_s[wb + j * HSTR + k4 * 4]);
#pragma unroll
            for (int i = 0; i < 8; ++i) {
#pragma unroll
                for (int j = 0; j < 8; ++j) {
                    float a = acc[i][j];
                    a = fmaf(hv[i].x, wv[j].x, a);
                    a = fmaf(hv[i].y, wv[j].y, a);
                    a = fmaf(hv[i].z, wv[j].z, a);
                    a = fmaf(hv[i].w, wv[j].w, a);
                    acc[i][j] = a;
                }
            }
        }
        __syncthreads();
    }

    // ---- stage logits to LDS (ls aliases the now-dead h tile) ----
#pragma unroll
    for (int i = 0; i < 8; ++i)
#pragma unroll
        for (int j = 0; j < 8; ++j)
            ls[tg * 8 + i][eg * 8 + j] = acc[i][j];

    __syncthreads();

    const size_t P = (size_t)NTOK * NEXP;
    float* __restrict__ o_mask = out;
    float* __restrict__ o_prob = out + P;
    float* __restrict__ o_lc   = out + 2 * P;
    float* __restrict__ o_lsl  = out + 3 * P;
    const size_t base = (size_t)t0 * NEXP;

    // ---- coalesced writes of logits_clean / logits_sel (64 elems/thread) ----
#pragma unroll 8
    for (int i = 0; i < 64; ++i) {
        const int f = i * 128 + tid;
        const int t = f >> 6, e = f & 63;
        const float lv = ls[t][e];
        const bool tmt = tok_mask(tmask, t0 + t, mmode);
        o_lc[base + f]  = lv;
        o_lsl[base + f] = tmt ? lv : -INFINITY;
    }

    // ---- epilogue: each wave handles 64 tokens, one per lane ----
    {
        const int lt = wave * 64 + lane;
        const bool tm = tok_mask(tmask, t0 + lt, mmode);

        unsigned long long bits = 0ULL;
        float m0 = -INFINITY;
        for (int r = 0; r < TOPK; ++r) {
            float bv = -INFINITY; int bi = 0;
            for (int e = 0; e < 64; ++e) {
                if ((bits >> e) & 1ULL) continue;
                const float x = ls[lt][e];
                if (x > bv) { bv = x; bi = e; }
            }
            bits |= 1ULL << bi;
            if (r == 0) m0 = bv;
        }

        float ssum = 0.f;
        for (int e = 0; e < 64; ++e)
            if ((bits >> e) & 1ULL) ssum += expf(ls[lt][e] - m0);

        sm_m0[lt]  = m0;
        sm_inv[lt] = 1.0f / ssum;
        mb[lt] = tm ? bits : 0ULL;            // mb==0 encodes masked token
    }

    __syncthreads();

    // ---- coalesced writes of probs / mask (computed on the fly) ----
#pragma unroll 8
    for (int i = 0; i < 64; ++i) {
        const int f = i * 128 + tid;
        const int t = f >> 6, e = f & 63;
        const unsigned long long bt = mb[t];
        const bool sel = ((bt >> e) & 1ULL) != 0ULL;
        o_prob[base + f] = sel ? expf(ls[t][e] - sm_m0[t]) * sm_inv[t] : 0.f;
        o_mask[base + f] = sel ? 1.0f : 0.0f;
    }
}

extern "C" void kernel_launch(void* const* d_in, const int* in_sizes, int n_in,
                              void* d_out, int out_size, void* d_ws, size_t ws_size,
                              hipStream_t stream)
{
    const float* h = (const float*)d_in[0];
    const float* W = (const float*)d_in[1];
    const void*  tmask = (const void*)d_in[2];
    float* out = (float*)d_out;

    hipLaunchKernelGGL(router_v9, dim3(NTOK / BTOK), dim3(128), 0, stream,
                       h, W, tmask, out);
}